// Round 18
// baseline (531.505 us; speedup 1.0000x reference)
//
#include <hip/hip_runtime.h>
#include <cstdint>
#include <cstddef>

// DGCNN forward. R29: R28 + dual MFMA accumulators in fused_dist_knn.
// R28 showed fused is latency-bound (VALUBusy 40->37% but dur flat). The
// unattacked chain: all 12 (C=128) / 6 (C=64) MFMAs per iteration accumulate
// into ONE acc -> ~360cyc serial per iter, only 4 chains/SIMD to hide it
// (MfmaUtil 15%). R29 splits into two independent accumulators (even/odd
// K-blocks) summed at the end: half the dependent chain, 2x MFMA ILP.
// Numerics: one fp32 reassociation ~1ulp ~1e-7 relative -- 3 orders below the
// ~1e-4 knn tolerance calibrated in R25. Everything else identical to R28.

constexpr int NB = 8;
constexpr int NP = 2048;
constexpr int KK = 20;

typedef short bf16x8 __attribute__((ext_vector_type(8)));
typedef float f32x16 __attribute__((ext_vector_type(16)));
typedef float f32x4 __attribute__((ext_vector_type(4)));

__device__ __forceinline__ f32x16 MF(bf16x8 a, bf16x8 b, f32x16 c) {
  return __builtin_amdgcn_mfma_f32_32x32x16_bf16(a, b, c, 0, 0, 0);
}
__device__ __forceinline__ f32x4 MF16(bf16x8 a, bf16x8 b, f32x4 c) {
  return __builtin_amdgcn_mfma_f32_16x16x32_bf16(a, b, c, 0, 0, 0);
}
__device__ __forceinline__ unsigned short bfh(float f) {
  return (unsigned short)(__float_as_uint(f) >> 16);  // truncating bf16
}
__device__ __forceinline__ float bff(unsigned short u) {
  return __uint_as_float(((unsigned)u) << 16);
}
__device__ __forceinline__ void split2(float v, unsigned short& h, unsigned short& l) {
  h = bfh(v); l = bfh(v - bff(h));
}
// rotation swizzle: rotate within each 32-col segment by 4*(owner&7) words.
__device__ __forceinline__ int PHYS(int c) {
  return (c & ~31) | ((c + 4 * ((c >> 5) & 7)) & 31);
}
// monotone key: flip float bits (3-inst form), embed (31 - pos) in low 5 bits.
__device__ __forceinline__ unsigned packkey(float d, int col) {
  const unsigned u = __float_as_uint(d);
  const unsigned k = u ^ (((unsigned)((int)u >> 31)) | 0x80000000u);
  return (k & ~31u) | (31u - ((unsigned)col & 31u));
}

// full-wave unsigned max via DPP (identity 0); uniform result in all lanes.
__device__ __forceinline__ unsigned wavemaxu(unsigned v) {
  int x = (int)v, t;
  t = __builtin_amdgcn_update_dpp(0, x, 0x111, 0xf, 0xf, false);  // row_shr:1
  x = (int)(((unsigned)x > (unsigned)t) ? (unsigned)x : (unsigned)t);
  t = __builtin_amdgcn_update_dpp(0, x, 0x112, 0xf, 0xf, false);  // row_shr:2
  x = (int)(((unsigned)x > (unsigned)t) ? (unsigned)x : (unsigned)t);
  t = __builtin_amdgcn_update_dpp(0, x, 0x114, 0xf, 0xf, false);  // row_shr:4
  x = (int)(((unsigned)x > (unsigned)t) ? (unsigned)x : (unsigned)t);
  t = __builtin_amdgcn_update_dpp(0, x, 0x118, 0xf, 0xf, false);  // row_shr:8
  x = (int)(((unsigned)x > (unsigned)t) ? (unsigned)x : (unsigned)t);
  t = __builtin_amdgcn_update_dpp(0, x, 0x142, 0xf, 0xf, false);  // row_bcast15
  x = (int)(((unsigned)x > (unsigned)t) ? (unsigned)x : (unsigned)t);
  t = __builtin_amdgcn_update_dpp(0, x, 0x143, 0xf, 0xf, false);  // row_bcast31
  x = (int)(((unsigned)x > (unsigned)t) ? (unsigned)x : (unsigned)t);
  return (unsigned)__builtin_amdgcn_readlane(x, 63);
}

// ---------------- pad x -> x4, plus L0 norms ----------------
__global__ __launch_bounds__(256) void pad_norms(const float* __restrict__ x,
    float* __restrict__ x4, float* __restrict__ nrm) {
  const int p = blockIdx.x * 256 + threadIdx.x;  // 16384
  float4 v;
  v.x = x[p * 3 + 0]; v.y = x[p * 3 + 1]; v.z = x[p * 3 + 2]; v.w = 0.f;
  *reinterpret_cast<float4*>(x4 + (size_t)p * 4) = v;
  nrm[p] = v.x * v.x + v.y * v.y + v.z * v.z;
}

// ---------------- all weight splits, fragment-order output ----------------
__global__ __launch_bounds__(256) void wsplit_all(const float* __restrict__ W1,
    const float* __restrict__ W2, const float* __restrict__ W3,
    const float* __restrict__ Wf,
    unsigned short* __restrict__ wb1, unsigned short* __restrict__ wb2,
    unsigned short* __restrict__ wb3,
    unsigned short* __restrict__ wfh, unsigned short* __restrict__ wfl) {
  const int id = blockIdx.x * 256 + threadIdx.x;  // 569344 total
  if (id < 524288) {
    const int row = id >> 9, c = id & 511;
    unsigned short h, l;
    split2(Wf[id], h, l);
    const size_t a = ((((size_t)(row >> 6)) * 64 + (c >> 3)) * 64 + (row & 63)) * 8 + (c & 7);
    wfh[a] = h; wfl[a] = l;
    return;
  }
  int id2 = id - 524288;
  const float* W; unsigned short* wb; int O, C;
  if (id2 < 4096)      { W = W1; wb = wb1; O = 64;  C = 64;  }
  else if (id2 < 12288){ W = W2; wb = wb2; O = 128; C = 64;  id2 -= 4096; }
  else                 { W = W3; wb = wb3; O = 256; C = 128; id2 -= 12288; }
  const int o = id2 / C, c = id2 % C;
  const int K8 = C >> 3;
  const float w1 = W[o * 2 * C + c];
  const float w2 = W[o * 2 * C + C + c];
  unsigned short h, l;
  const int r1 = o, rd = O + o;
  const size_t a1 = (((size_t)(r1 >> 6) * K8 + (c >> 3)) * 64 + (r1 & 63)) * 8 + (c & 7);
  const size_t ad = (((size_t)(rd >> 6) * K8 + (c >> 3)) * 64 + (rd & 63)) * 8 + (c & 7);
  split2(w1, h, l);
  wb[a1] = h; wb[2 * O * C + a1] = l;
  split2(w2 - w1, h, l);
  wb[ad] = h; wb[2 * O * C + ad] = l;
}

// ---------------- top-20 select on packed keys (R23 semantics) ------------------
__device__ __forceinline__ void select20(unsigned* __restrict__ srow,
    const int lane, int* __restrict__ op) {
  const int i31 = lane & 31;
  const int rot = 4 * (lane & 7);
  unsigned k1 = 0u, k2 = 0u;
#pragma unroll
  for (int q = 0; q < 8; ++q) {
    const uint4 v4 = *reinterpret_cast<const uint4*>(srow + lane * 32 + ((4 * q + rot) & 31));
    {
      const unsigned e = v4.x, lo = (k1 < e) ? k1 : e;
      k1 = (k1 > e) ? k1 : e; k2 = (k2 > lo) ? k2 : lo;
    }
    {
      const unsigned e = v4.y, lo = (k1 < e) ? k1 : e;
      k1 = (k1 > e) ? k1 : e; k2 = (k2 > lo) ? k2 : lo;
    }
    {
      const unsigned e = v4.z, lo = (k1 < e) ? k1 : e;
      k1 = (k1 > e) ? k1 : e; k2 = (k2 > lo) ? k2 : lo;
    }
    {
      const unsigned e = v4.w, lo = (k1 < e) ? k1 : e;
      k1 = (k1 > e) ? k1 : e; k2 = (k2 > lo) ? k2 : lo;
    }
  }
  int mycol = 0;
#pragma unroll
  for (int r = 0; r < KK; ++r) {
    const unsigned wm = wavemaxu(k1);
    const unsigned long long bal = __ballot(k1 == wm);
    const int wl = bal ? (__ffsll(bal) - 1) : 0;
    const int mwin = 31 - (int)(wm & 31u);
    const int col = wl * 32 + mwin;
    if (lane == r) mycol = col;
    if (lane == 0) srow[wl * 32 + ((mwin + 4 * (wl & 7)) & 31)] = 0u;  // poke
    if (lane == wl) { k1 = k2; k2 = 0u; }
    // only a twice-popped winner can have k1==0 (real keys are never 0)
    if (__ballot(k1 == 0u)) {
      asm volatile("s_waitcnt lgkmcnt(0)" ::: "memory");  // drain pokes
      __builtin_amdgcn_sched_barrier(0);                  // rule #18 fence
      const unsigned e = srow[wl * 32 + ((i31 + 4 * (wl & 7)) & 31)];
      const unsigned nm = wavemaxu(e);                    // poked slots = 0
      if (lane == wl) k1 = nm;
    }
  }
  if (lane < KK) op[lane] = mycol;  // coalesced 20-lane store
}

// ---------------- fused dist+knn, L0 (C=3, fp32) ----------------
__global__ __launch_bounds__(1024) void fused_dist_knn0(const float* __restrict__ X4,
    const float* __restrict__ norms, int* __restrict__ idxout) {
  __shared__ unsigned sdist[16][2048];
  const int t = threadIdx.x, lane = t & 63, w = t >> 6;  // w: 0..15
  const int l15 = lane & 15, g4 = lane >> 4;
  const int bid = blockIdx.x;          // 1024
  const int b = bid & 7, g = bid >> 3; // XCD-batch affinity
  const int i0 = g * 16;

  float4 rx[4]; float ni[4];
#pragma unroll
  for (int e = 0; e < 4; ++e) {
    const int p = b * NP + i0 + g4 * 4 + e;
    rx[e] = *reinterpret_cast<const float4*>(X4 + (size_t)p * 4);
    ni[e] = norms[p];
  }

  const int jl0 = w * 16 + l15;
  const float* px = X4 + (size_t)(b * NP + jl0) * 4;
  const float* pn = norms + b * NP + jl0;
  const int ps0 = PHYS(jl0);
#pragma unroll
  for (int it = 0; it < 8; ++it) {
    const float4 cj = *reinterpret_cast<const float4*>(px + (size_t)it * 1024);
    const float nj = pn[it * 256];
    const int ps = ps0 + it * 256;
#pragma unroll
    for (int e = 0; e < 4; ++e) {
      float acc = fmaf(rx[e].x, cj.x, 0.f);
      acc = fmaf(rx[e].y, cj.y, acc);
      acc = fmaf(rx[e].z, cj.z, acc);
      sdist[g4 * 4 + e][ps] = packkey(2.f * acc - ni[e] - nj, jl0);
    }
  }
  __syncthreads();

  select20(&sdist[w][0], lane, idxout + (size_t)(b * NP + i0 + w) * KK);
}

// ---------------- fused dist+knn (l>=1): dual-acc MFMA, hoisted addressing ------
template<int C>
__global__ __launch_bounds__(1024) void fused_dist_knn(const unsigned short* __restrict__ xh,
    const unsigned short* __restrict__ xl, int colbase,
    const float* __restrict__ norms, int* __restrict__ idxout) {
  constexpr int KB = C / 32;  // K-blocks per chain (2 or 4)
  __shared__ unsigned sdist[16][2048];
  const int t = threadIdx.x, lane = t & 63, w = t >> 6;  // w: 0..15
  const int l15 = lane & 15, g4 = lane >> 4;
  const int bid = blockIdx.x;          // 1024
  const int b = bid & 7, g = bid >> 3; // XCD-batch affinity
  const int i0 = g * 16;
  const int ti = (b * NP + i0) >> 6;
  const int ir = i0 & 63;
  const int k8b = colbase >> 3;

  bf16x8 AH[KB], AL[KB];
#pragma unroll
  for (int kb = 0; kb < KB; ++kb) {
    const size_t a = (((size_t)ti * 64 + k8b + kb * 4 + g4) * 64 + ir + l15) * 8;
    AH[kb] = *reinterpret_cast<const bf16x8*>(xh + a);
    AL[kb] = *reinterpret_cast<const bf16x8*>(xl + a);
  }
  float ni[4];
#pragma unroll
  for (int e = 0; e < 4; ++e) ni[e] = norms[b * NP + i0 + g4 * 4 + e];

  const int tj0 = (b * NP + w * 16) >> 6;
  const int jr0 = (w * 16) & 63;
  const unsigned short* pbh[KB];
  const unsigned short* pbl[KB];
#pragma unroll
  for (int kb = 0; kb < KB; ++kb) {
    const size_t a = (((size_t)tj0 * 64 + k8b + kb * 4 + g4) * 64 + jr0 + l15) * 8;
    pbh[kb] = xh + a;
    pbl[kb] = xl + a;
  }
  const int jl0 = w * 16 + l15;
  const float* pnj = norms + b * NP + jl0;
  const int ps0 = PHYS(jl0);

#pragma unroll
  for (int it = 0; it < 8; ++it) {
    bf16x8 BH[KB], BL[KB];
#pragma unroll
    for (int kb = 0; kb < KB; ++kb) {
      BH[kb] = *reinterpret_cast<const bf16x8*>(pbh[kb] + (size_t)it * 131072);
      BL[kb] = *reinterpret_cast<const bf16x8*>(pbl[kb] + (size_t)it * 131072);
    }
    // dual accumulators: even/odd K-blocks run independent MFMA chains.
    f32x4 accA = {0.f, 0.f, 0.f, 0.f};
    f32x4 accB = {0.f, 0.f, 0.f, 0.f};
#pragma unroll
    for (int kb = 0; kb < KB; kb += 2) {
      accA = MF16(AH[kb], BH[kb], accA);
      accB = MF16(AH[kb + 1], BH[kb + 1], accB);
      accA = MF16(AH[kb], BL[kb], accA);
      accB = MF16(AH[kb + 1], BL[kb + 1], accB);
      accA = MF16(AL[kb], BH[kb], accA);
      accB = MF16(AL[kb + 1], BH[kb + 1], accB);
    }
    const float nj = pnj[it * 256];
    const int ps = ps0 + it * 256;
#pragma unroll
    for (int e = 0; e < 4; ++e) {
      const float d = accA[e] + accB[e];
      sdist[g4 * 4 + e][ps] = packkey(2.f * d - ni[e] - nj, jl0);
    }
  }
  __syncthreads();

  select20(&sdist[w][0], lane, idxout + (size_t)(b * NP + i0 + w) * KK);
}

// ---------------- per-point GEMM, L0 (C=3, fp32 vector) ----------------
__global__ __launch_bounds__(256) void pt_gemm0(const float* __restrict__ x,
    const float* __restrict__ W, const float* __restrict__ bias,
    float* __restrict__ Y, float* __restrict__ T) {
  const int t = threadIdx.x;
  const int o = t & 63;
  const int g = blockIdx.x * 4 + (t >> 6);  // 0..16383
  const float x0 = x[(size_t)g * 3 + 0], x1 = x[(size_t)g * 3 + 1], x2 = x[(size_t)g * 3 + 2];
  const float w10 = W[o * 6 + 0], w11 = W[o * 6 + 1], w12 = W[o * 6 + 2];
  const float w20 = W[o * 6 + 3], w21 = W[o * 6 + 4], w22 = W[o * 6 + 5];
  Y[(size_t)g * 64 + o] = w10 * x0 + w11 * x1 + w12 * x2;
  T[(size_t)g * 64 + o] = (w20 - w10) * x0 + (w21 - w11) * x1 + (w22 - w12) * x2 + bias[o];
}

// ---------------- per-point GEMM (l>=1): 2 n-tiles/block, B-frag reuse ----------
template<int C, int O2>  // O2 = 2*O
__global__ __launch_bounds__(256) void pt_gemm(const unsigned short* __restrict__ xh,
    const unsigned short* __restrict__ xl, int colbase,
    const unsigned short* __restrict__ wch, const unsigned short* __restrict__ wcl,
    const float* __restrict__ bias, float* __restrict__ Y, float* __restrict__ T) {
  constexpr int K8 = C / 8;
  constexpr int H = K8 / 2;
  constexpr int O = O2 / 2;
  const int t = threadIdx.x, lane = t & 63, w = t >> 6;
  const int half = lane >> 5, l31 = lane & 31;
  const int rt = (w >> 1) * 32, tc = (w & 1) * 32;
  const int n0 = blockIdx.x * 128, o0 = blockIdx.y * 64;  // 2 n-tiles per block
  const int tn0 = n0 >> 6, tn1 = tn0 + 1, to = o0 >> 6;
  const int k8b = colbase >> 3;
  const int col = o0 + tc + l31;

  bf16x8 BH[H], BL[H];
#pragma unroll
  for (int ch = 0; ch < H; ++ch) {
    const size_t a = (((size_t)to * K8 + ch * 2 + half) * 64 + tc + l31) * 8;
    BH[ch] = *reinterpret_cast<const bf16x8*>(wch + a);
    BL[ch] = *reinterpret_cast<const bf16x8*>(wcl + a);
  }

  f32x16 acc0, acc1;
#pragma unroll
  for (int i = 0; i < 16; ++i) { acc0[i] = 0.f; acc1[i] = 0.f; }
#pragma unroll
  for (int ch = 0; ch < H; ++ch) {
    const size_t a0 = (((size_t)tn0 * 64 + k8b + ch * 2 + half) * 64 + rt + l31) * 8;
    const size_t a1 = (((size_t)tn1 * 64 + k8b + ch * 2 + half) * 64 + rt + l31) * 8;
    const bf16x8 ah0 = *reinterpret_cast<const bf16x8*>(xh + a0);
    const bf16x8 al0 = *reinterpret_cast<const bf16x8*>(xl + a0);
    const bf16x8 ah1 = *reinterpret_cast<const bf16x8*>(xh + a1);
    const bf16x8 al1 = *reinterpret_cast<const bf16x8*>(xl + a1);
    acc0 = MF(ah0, BH[ch], acc0); acc1 = MF(ah1, BH[ch], acc1);
    acc0 = MF(ah0, BL[ch], acc0); acc1 = MF(ah1, BL[ch], acc1);
    acc0 = MF(al0, BH[ch], acc0); acc1 = MF(al1, BH[ch], acc1);
  }

  if (col < O) {
#pragma unroll
    for (int i = 0; i < 16; ++i) {
      const int rr = rt + (i & 3) + 8 * (i >> 2) + 4 * half;
      Y[(size_t)(n0 + rr) * O + col] = acc0[i];
      Y[(size_t)(n0 + 64 + rr) * O + col] = acc1[i];
    }
  } else {
    const float bv = bias[col - O];
#pragma unroll
    for (int i = 0; i < 16; ++i) {
      const int rr = rt + (i & 3) + 8 * (i >> 2) + 4 * half;
      T[(size_t)(n0 + rr) * O + (col - O)] = acc0[i] + bv;
      T[(size_t)(n0 + 64 + rr) * O + (col - O)] = acc1[i] + bv;
    }
  }
}

// ---------------- edge reduce: max/sum/sumsq over gathered Y rows ----------------
template<int O, int PTS>
__global__ __launch_bounds__(256) void edge_reduce(const float* __restrict__ Y,
    const float* __restrict__ T, const int* __restrict__ idx,
    float* __restrict__ outmax, float* __restrict__ ssum, float* __restrict__ ssq) {
  constexpr int CQ = O / 4;      // channel-quad groups
  constexpr int NG = 256 / CQ;   // point groups per block
  constexpr int PPT = PTS / NG;  // points per thread
  constexpr int BPB = NP / PTS;  // blocks per batch (128)
  __shared__ int sidx[PTS * KK];
  __shared__ float sred[1024], qred[1024];
  const int t = threadIdx.x;
  const int cq = t % CQ, ng = t / CQ;
  const int c = cq * 4;
  const int bid = blockIdx.x;    // 1024 blocks total
  const int g0 = ((bid & 7) * BPB + (bid >> 3)) * PTS;  // XCD-affinity swizzle

  for (int i = t; i < PTS * KK; i += 256) sidx[i] = idx[(size_t)g0 * KK + i];
  __syncthreads();

  float s4[4] = {}, q4[4] = {};
#pragma unroll
  for (int pp = 0; pp < PPT; ++pp) {
    const int p = ng + pp * NG;
    const int g = g0 + p;
    const int base = (g >> 11) * NP;
    const float4 tv = *reinterpret_cast<const float4*>(T + (size_t)g * O + c);
    float4 vs[KK];
#pragma unroll
    for (int k = 0; k < KK; ++k)
      vs[k] = *reinterpret_cast<const float4*>(Y + (size_t)(base + sidx[p * KK + k]) * O + c);
    float m0 = -__builtin_inff(), m1 = m0, m2 = m0, m3 = m0;
#pragma unroll
    for (int k = 0; k < KK; ++k) {
      const float h0 = vs[k].x + tv.x, h1 = vs[k].y + tv.y;
      const float h2 = vs[k].z + tv.z, h3 = vs[k].w + tv.w;
      m0 = fmaxf(m0, h0); m1 = fmaxf(m1, h1); m2 = fmaxf(m2, h2); m3 = fmaxf(m3, h3);
      s4[0] += h0; s4[1] += h1; s4[2] += h2; s4[3] += h3;
      q4[0] = fmaf(h0, h0, q4[0]); q4[1] = fmaf(h1, h1, q4[1]);
      q4[2] = fmaf(h2, h2, q4[2]); q4[3] = fmaf(h3, h3, q4[3]);
    }
    float4 o4; o4.x = m0; o4.y = m1; o4.z = m2; o4.w = m3;
    *reinterpret_cast<float4*>(outmax + (size_t)g * O + c) = o4;
  }

#pragma unroll
  for (int j = 0; j < 4; ++j) { sred[t * 4 + j] = s4[j]; qred[t * 4 + j] = q4[j]; }
  __syncthreads();
  if (t < O) {
    const int cqr = t >> 2, jr = t & 3;
    float s = 0.f, q = 0.f;
#pragma unroll
    for (int n = 0; n < NG; ++n) {
      s += sred[(n * CQ + cqr) * 4 + jr];
      q += qred[(n * CQ + cqr) * 4 + jr];
    }
    atomicAdd(ssum + t, s);
    atomicAdd(ssq + t, q);
  }
}

// ---------------- bn + leaky relu -> fragment-order bf16 planes ----------------
template<int O, bool WN>
__global__ __launch_bounds__(256) void bnrelu_kernel(const float* __restrict__ fA,
    const float* __restrict__ ssum, const float* __restrict__ ssq,
    const float* __restrict__ g, const float* __restrict__ be,
    unsigned short* __restrict__ xh, unsigned short* __restrict__ xl, int colbase,
    float* __restrict__ nrm) {
  constexpr float INV = 1.0f / 327680.0f;  // B*N*K
  constexpr int K8 = O / 8;
  const int id = blockIdx.x * 256 + threadIdx.x;  // 16384*K8 items
  const int r = id & 63;
  const int k8loc = (id >> 6) % K8;
  const int tile = (id >> 6) / K8;
  const int n = tile * 64 + r;
  const int c0 = k8loc * 8;

  float hv[8];
  {
    const float4 p0 = *reinterpret_cast<const float4*>(fA + (size_t)n * O + c0);
    const float4 p1 = *reinterpret_cast<const float4*>(fA + (size_t)n * O + c0 + 4);
    hv[0] = p0.x; hv[1] = p0.y; hv[2] = p0.z; hv[3] = p0.w;
    hv[4] = p1.x; hv[5] = p1.y; hv[6] = p1.z; hv[7] = p1.w;
  }
  unsigned short hh[8], ll[8];
  float s = 0.f;
#pragma unroll
  for (int j = 0; j < 8; ++j) {
    const int col = c0 + j;
    const float m = ssum[col] * INV;
    const float v = ssq[col] * INV - m * m;
    const float sc = g[col] / sqrtf(v + 1e-5f);
    float val = (hv[j] - m) * sc + be[col];
    val = (val >= 0.f) ? val : 0.2f * val;
    split2(val, hh[j], ll[j]);
    const float recon = bff(hh[j]) + bff(ll[j]);
    s = fmaf(recon, recon, s);
  }
  const size_t ob = (((size_t)tile * 64 + (colbase >> 3) + k8loc) * 64 + r) * 8;
  uint4 ph, pl;
  ph.x = (unsigned)hh[0] | ((unsigned)hh[1] << 16);
  ph.y = (unsigned)hh[2] | ((unsigned)hh[3] << 16);
  ph.z = (unsigned)hh[4] | ((unsigned)hh[5] << 16);
  ph.w = (unsigned)hh[6] | ((unsigned)hh[7] << 16);
  pl.x = (unsigned)ll[0] | ((unsigned)ll[1] << 16);
  pl.y = (unsigned)ll[2] | ((unsigned)ll[3] << 16);
  pl.z = (unsigned)ll[4] | ((unsigned)ll[5] << 16);
  pl.w = (unsigned)ll[6] | ((unsigned)ll[7] << 16);
  *reinterpret_cast<uint4*>(xh + ob) = ph;
  *reinterpret_cast<uint4*>(xl + ob) = pl;
  if (WN) atomicAdd(nrm + n, s);
}

// ---------------- final conv + max pool: 2 n-tiles/block, B-frag reuse ----------
__global__ __launch_bounds__(256) void final_mfma(const unsigned short* __restrict__ xh,
    const unsigned short* __restrict__ wfh, unsigned* __restrict__ outenc) {
  __shared__ float fr[128];
  const int t = threadIdx.x, lane = t & 63, w = t >> 6;
  const int half = lane >> 5, l31 = lane & 31;
  const int rt = (w >> 1) * 32, tc = (w & 1) * 32;
  const int b = blockIdx.z, n0 = blockIdx.x * 128, o0 = blockIdx.y * 64;
  const int tn0 = (b * NP + n0) >> 6, tn1 = tn0 + 1, to = o0 >> 6;

  f32x16 acc0, acc1;
#pragma unroll
  for (int i = 0; i < 16; ++i) { acc0[i] = 0.f; acc1[i] = 0.f; }

#pragma unroll
  for (int cc = 0; cc < 4; ++cc) {  // 128 channels per chunk
    bf16x8 BH[8];
#pragma unroll
    for (int ch = 0; ch < 8; ++ch) {
      const int k8 = cc * 16 + ch * 2 + half;
      const size_t a = (((size_t)to * 64 + k8) * 64 + tc + l31) * 8;
      BH[ch] = *reinterpret_cast<const bf16x8*>(wfh + a);
    }
#pragma unroll
    for (int ch = 0; ch < 8; ++ch) {
      const int k8 = cc * 16 + ch * 2 + half;
      const size_t a0 = (((size_t)tn0 * 64 + k8) * 64 + rt + l31) * 8;
      const size_t a1 = (((size_t)tn1 * 64 + k8) * 64 + rt + l31) * 8;
      const bf16x8 ah0 = *reinterpret_cast<const bf16x8*>(xh + a0);
      const bf16x8 ah1 = *reinterpret_cast<const bf16x8*>(xh + a1);
      acc0 = MF(ah0, BH[ch], acc0);
      acc1 = MF(ah1, BH[ch], acc1);
    }
  }

  float M = fmaxf(acc0[0], acc1[0]);
#pragma unroll
  for (int i = 1; i < 16; ++i) M = fmaxf(M, fmaxf(acc0[i], acc1[i]));
  M = fmaxf(M, __shfl_xor(M, 32));
  fr[w * 32 + l31] = M;
  __syncthreads();
  if (t < 64) {
    const float Mc = fmaxf(fr[t], fr[64 + t]);
    const unsigned ub = __float_as_uint(Mc);
    const unsigned key = (ub & 0x80000000u) ? ~ub : (ub | 0x80000000u);
    atomicMax(outenc + b * 1024 + o0 + t, key);
  }
}

__global__ __launch_bounds__(256) void decode_kernel(const unsigned int* __restrict__ enc,
    const float* __restrict__ bf, float* __restrict__ out) {
  const int gid = blockIdx.x * 256 + threadIdx.x;  // 8192
  const unsigned key = enc[gid];
  const unsigned ubits = (key & 0x80000000u) ? (key & 0x7fffffffu) : ~key;
  out[gid] = __uint_as_float(ubits) + bf[gid & 1023];
}

// ---------------- launch ----------------
extern "C" void kernel_launch(void* const* d_in, const int* in_sizes, int n_in,
                              void* d_out, int out_size, void* d_ws, size_t ws_size,
                              hipStream_t stream) {
  (void)in_sizes; (void)n_in; (void)out_size; (void)ws_size;
  const float* x   = (const float*)d_in[0];
  const float* W0  = (const float*)d_in[1];
  const float* b0  = (const float*)d_in[2];
  const float* g0  = (const float*)d_in[3];
  const float* be0 = (const float*)d_in[4];
  const float* W1  = (const float*)d_in[5];
  const float* b1  = (const float*)d_in[6];
  const float* g1  = (const float*)d_in[7];
  const float* be1 = (const float*)d_in[8];
  const float* W2  = (const float*)d_in[9];
  const float* b2  = (const float*)d_in[10];
  const float* g2  = (const float*)d_in[11];
  const float* be2 = (const float*)d_in[12];
  const float* W3  = (const float*)d_in[13];
  const float* b3  = (const float*)d_in[14];
  const float* g3  = (const float*)d_in[15];
  const float* be3 = (const float*)d_in[16];
  const float* Wf  = (const float*)d_in[17];
  const float* bf  = (const float*)d_in[18];

  float* wsf = (float*)d_ws;
  int* idxb = (int*)d_ws;                        // 327,680 ints
  float* stats = wsf + 327680;                   // 2048
  float* nb = wsf + 329728;                      // 4 x 16384 norm buffers
  unsigned* outenc = (unsigned*)(wsf + 395264);  // 8192
  float* x4 = wsf + 403456;                      // 65536
  float* featA = wsf + 468992;                   // 16384*256
  float* negd = wsf + 4663296;                   // scratch region (Y/T)
  float* Yb = negd;
  float* Tb = negd + 4194304;
  unsigned short* xh = (unsigned short*)(wsf + 21440512);  // xT hi plane
  unsigned short* xl = xh + 8388608;                       // xT lo plane
  unsigned short* wb1 = xl + 8388608;            // 2*(2*64*64)   = 16384
  unsigned short* wb2 = wb1 + 16384;             // 2*(2*128*64)  = 32768
  unsigned short* wb3 = wb2 + 32768;             // 2*(2*256*128) = 131072
  unsigned short* wfh = wb3 + 131072;            // 1024*512
  unsigned short* wfl = wfh + 524288;

  float* normsA = nb, *normsB = nb + 16384, *normsC = nb + 32768, *normsD = nb + 49152;

  hipMemsetAsync(stats, 0, (2048 + 65536) * sizeof(float), stream);
  hipMemsetAsync(outenc, 0, 8192 * sizeof(unsigned), stream);

  const dim3 blk(256, 1, 1);
  const dim3 fblk(1024, 1, 1);
  const dim3 fgrid(1024, 1, 1);
  const dim3 ergrid(1024, 1, 1);

  pad_norms<<<dim3(64), blk, 0, stream>>>(x, x4, normsA);
  wsplit_all<<<dim3(2224), blk, 0, stream>>>(W1, W2, W3, Wf, wb1, wb2, wb3, wfh, wfl);

  // Layer 0 (C=3 -> 64, out cols [0,64))
  fused_dist_knn0<<<fgrid, fblk, 0, stream>>>(x4, normsA, idxb);
  pt_gemm0<<<dim3(4096), blk, 0, stream>>>(x, W0, b0, Yb, Tb);
  edge_reduce<64, 16><<<ergrid, blk, 0, stream>>>(Yb, Tb, idxb, featA, stats, stats + 256);
  bnrelu_kernel<64, true><<<dim3(512), blk, 0, stream>>>(featA, stats, stats + 256,
      g0, be0, xh, xl, 0, normsB);

  // Layer 1 (64 -> 64, in cols [0,64), out [64,128))
  fused_dist_knn<64><<<fgrid, fblk, 0, stream>>>(xh, xl, 0, normsB, idxb);
  pt_gemm<64, 128><<<dim3(128, 2), blk, 0, stream>>>(xh, xl, 0, wb1, wb1 + 8192, b1, Yb, Tb);
  edge_reduce<64, 16><<<ergrid, blk, 0, stream>>>(Yb, Tb, idxb, featA, stats + 512, stats + 768);
  bnrelu_kernel<64, true><<<dim3(512), blk, 0, stream>>>(featA, stats + 512, stats + 768,
      g1, be1, xh, xl, 64, normsC);

  // Layer 2 (64 -> 128, in cols [64,128), out [128,256))
  fused_dist_knn<64><<<fgrid, fblk, 0, stream>>>(xh, xl, 64, normsC, idxb);
  pt_gemm<64, 256><<<dim3(128, 4), blk, 0, stream>>>(xh, xl, 64, wb2, wb2 + 16384, b2, Yb, Tb);
  edge_reduce<128, 16><<<ergrid, blk, 0, stream>>>(Yb, Tb, idxb, featA, stats + 1024, stats + 1280);
  bnrelu_kernel<128, true><<<dim3(1024), blk, 0, stream>>>(featA, stats + 1024, stats + 1280,
      g2, be2, xh, xl, 128, normsD);

  // Layer 3 (128 -> 256, in cols [128,256), out [256,512))
  fused_dist_knn<128><<<fgrid, fblk, 0, stream>>>(xh, xl, 128, normsD, idxb);
  pt_gemm<128, 512><<<dim3(128, 8), blk, 0, stream>>>(xh, xl, 128, wb3, wb3 + 65536, b3, Yb, Tb);
  edge_reduce<256, 16><<<ergrid, blk, 0, stream>>>(Yb, Tb, idxb, featA, stats + 1536, stats + 1792);
  bnrelu_kernel<256, false><<<dim3(2048), blk, 0, stream>>>(featA, stats + 1536, stats + 1792,
      g3, be3, xh, xl, 256, nullptr);

  // Final 1x1 conv + global max pool (single-plane, 2 n-tiles/block)
  final_mfma<<<dim3(16, 16, 8), blk, 0, stream>>>(xh, wfh, outenc);
  decode_kernel<<<dim3(32), blk, 0, stream>>>(outenc, bf, (float*)d_out);
}

// Round 19
// 478.272 us; speedup vs baseline: 1.1113x; 1.1113x over previous
//
#include <hip/hip_runtime.h>
#include <cstdint>
#include <cstddef>

// DGCNN forward. R30 = exact revert to R28 (session best, 472.5us).
// R29 post-mortem: dual MFMA accumulators pushed the fused kernel past the
// hard 64-VGPR cap imposed by __launch_bounds__(1024) -> compiler spilled
// B-fragments to SCRATCH (FETCH 4.2MB->76MB, WRITE 1.3KB->150MB per dispatch,
// 230MB HBM traffic, 120-224us) -> 531us total. Lesson: R28 sits exactly at
// the 64-VGPR boundary; ANY added live state in fused_dist_knn spills. The
// kernel's occupancy/latency trade is a verified local optimum. This file is
// byte-identical to R28.

constexpr int NB = 8;
constexpr int NP = 2048;
constexpr int KK = 20;

typedef short bf16x8 __attribute__((ext_vector_type(8)));
typedef float f32x16 __attribute__((ext_vector_type(16)));
typedef float f32x4 __attribute__((ext_vector_type(4)));

__device__ __forceinline__ f32x16 MF(bf16x8 a, bf16x8 b, f32x16 c) {
  return __builtin_amdgcn_mfma_f32_32x32x16_bf16(a, b, c, 0, 0, 0);
}
__device__ __forceinline__ f32x4 MF16(bf16x8 a, bf16x8 b, f32x4 c) {
  return __builtin_amdgcn_mfma_f32_16x16x32_bf16(a, b, c, 0, 0, 0);
}
__device__ __forceinline__ unsigned short bfh(float f) {
  return (unsigned short)(__float_as_uint(f) >> 16);  // truncating bf16
}
__device__ __forceinline__ float bff(unsigned short u) {
  return __uint_as_float(((unsigned)u) << 16);
}
__device__ __forceinline__ void split2(float v, unsigned short& h, unsigned short& l) {
  h = bfh(v); l = bfh(v - bff(h));
}
// rotation swizzle: rotate within each 32-col segment by 4*(owner&7) words.
__device__ __forceinline__ int PHYS(int c) {
  return (c & ~31) | ((c + 4 * ((c >> 5) & 7)) & 31);
}
// monotone key: flip float bits (3-inst form), embed (31 - pos) in low 5 bits.
__device__ __forceinline__ unsigned packkey(float d, int col) {
  const unsigned u = __float_as_uint(d);
  const unsigned k = u ^ (((unsigned)((int)u >> 31)) | 0x80000000u);
  return (k & ~31u) | (31u - ((unsigned)col & 31u));
}

// full-wave unsigned max via DPP (identity 0); uniform result in all lanes.
__device__ __forceinline__ unsigned wavemaxu(unsigned v) {
  int x = (int)v, t;
  t = __builtin_amdgcn_update_dpp(0, x, 0x111, 0xf, 0xf, false);  // row_shr:1
  x = (int)(((unsigned)x > (unsigned)t) ? (unsigned)x : (unsigned)t);
  t = __builtin_amdgcn_update_dpp(0, x, 0x112, 0xf, 0xf, false);  // row_shr:2
  x = (int)(((unsigned)x > (unsigned)t) ? (unsigned)x : (unsigned)t);
  t = __builtin_amdgcn_update_dpp(0, x, 0x114, 0xf, 0xf, false);  // row_shr:4
  x = (int)(((unsigned)x > (unsigned)t) ? (unsigned)x : (unsigned)t);
  t = __builtin_amdgcn_update_dpp(0, x, 0x118, 0xf, 0xf, false);  // row_shr:8
  x = (int)(((unsigned)x > (unsigned)t) ? (unsigned)x : (unsigned)t);
  t = __builtin_amdgcn_update_dpp(0, x, 0x142, 0xf, 0xf, false);  // row_bcast15
  x = (int)(((unsigned)x > (unsigned)t) ? (unsigned)x : (unsigned)t);
  t = __builtin_amdgcn_update_dpp(0, x, 0x143, 0xf, 0xf, false);  // row_bcast31
  x = (int)(((unsigned)x > (unsigned)t) ? (unsigned)x : (unsigned)t);
  return (unsigned)__builtin_amdgcn_readlane(x, 63);
}

// ---------------- pad x -> x4, plus L0 norms ----------------
__global__ __launch_bounds__(256) void pad_norms(const float* __restrict__ x,
    float* __restrict__ x4, float* __restrict__ nrm) {
  const int p = blockIdx.x * 256 + threadIdx.x;  // 16384
  float4 v;
  v.x = x[p * 3 + 0]; v.y = x[p * 3 + 1]; v.z = x[p * 3 + 2]; v.w = 0.f;
  *reinterpret_cast<float4*>(x4 + (size_t)p * 4) = v;
  nrm[p] = v.x * v.x + v.y * v.y + v.z * v.z;
}

// ---------------- all weight splits, fragment-order output ----------------
__global__ __launch_bounds__(256) void wsplit_all(const float* __restrict__ W1,
    const float* __restrict__ W2, const float* __restrict__ W3,
    const float* __restrict__ Wf,
    unsigned short* __restrict__ wb1, unsigned short* __restrict__ wb2,
    unsigned short* __restrict__ wb3,
    unsigned short* __restrict__ wfh, unsigned short* __restrict__ wfl) {
  const int id = blockIdx.x * 256 + threadIdx.x;  // 569344 total
  if (id < 524288) {
    const int row = id >> 9, c = id & 511;
    unsigned short h, l;
    split2(Wf[id], h, l);
    const size_t a = ((((size_t)(row >> 6)) * 64 + (c >> 3)) * 64 + (row & 63)) * 8 + (c & 7);
    wfh[a] = h; wfl[a] = l;
    return;
  }
  int id2 = id - 524288;
  const float* W; unsigned short* wb; int O, C;
  if (id2 < 4096)      { W = W1; wb = wb1; O = 64;  C = 64;  }
  else if (id2 < 12288){ W = W2; wb = wb2; O = 128; C = 64;  id2 -= 4096; }
  else                 { W = W3; wb = wb3; O = 256; C = 128; id2 -= 12288; }
  const int o = id2 / C, c = id2 % C;
  const int K8 = C >> 3;
  const float w1 = W[o * 2 * C + c];
  const float w2 = W[o * 2 * C + C + c];
  unsigned short h, l;
  const int r1 = o, rd = O + o;
  const size_t a1 = (((size_t)(r1 >> 6) * K8 + (c >> 3)) * 64 + (r1 & 63)) * 8 + (c & 7);
  const size_t ad = (((size_t)(rd >> 6) * K8 + (c >> 3)) * 64 + (rd & 63)) * 8 + (c & 7);
  split2(w1, h, l);
  wb[a1] = h; wb[2 * O * C + a1] = l;
  split2(w2 - w1, h, l);
  wb[ad] = h; wb[2 * O * C + ad] = l;
}

// ---------------- top-20 select on packed keys (R23 semantics) ------------------
__device__ __forceinline__ void select20(unsigned* __restrict__ srow,
    const int lane, int* __restrict__ op) {
  const int i31 = lane & 31;
  const int rot = 4 * (lane & 7);
  unsigned k1 = 0u, k2 = 0u;
#pragma unroll
  for (int q = 0; q < 8; ++q) {
    const uint4 v4 = *reinterpret_cast<const uint4*>(srow + lane * 32 + ((4 * q + rot) & 31));
    {
      const unsigned e = v4.x, lo = (k1 < e) ? k1 : e;
      k1 = (k1 > e) ? k1 : e; k2 = (k2 > lo) ? k2 : lo;
    }
    {
      const unsigned e = v4.y, lo = (k1 < e) ? k1 : e;
      k1 = (k1 > e) ? k1 : e; k2 = (k2 > lo) ? k2 : lo;
    }
    {
      const unsigned e = v4.z, lo = (k1 < e) ? k1 : e;
      k1 = (k1 > e) ? k1 : e; k2 = (k2 > lo) ? k2 : lo;
    }
    {
      const unsigned e = v4.w, lo = (k1 < e) ? k1 : e;
      k1 = (k1 > e) ? k1 : e; k2 = (k2 > lo) ? k2 : lo;
    }
  }
  int mycol = 0;
#pragma unroll
  for (int r = 0; r < KK; ++r) {
    const unsigned wm = wavemaxu(k1);
    const unsigned long long bal = __ballot(k1 == wm);
    const int wl = bal ? (__ffsll(bal) - 1) : 0;
    const int mwin = 31 - (int)(wm & 31u);
    const int col = wl * 32 + mwin;
    if (lane == r) mycol = col;
    if (lane == 0) srow[wl * 32 + ((mwin + 4 * (wl & 7)) & 31)] = 0u;  // poke
    if (lane == wl) { k1 = k2; k2 = 0u; }
    // only a twice-popped winner can have k1==0 (real keys are never 0)
    if (__ballot(k1 == 0u)) {
      asm volatile("s_waitcnt lgkmcnt(0)" ::: "memory");  // drain pokes
      __builtin_amdgcn_sched_barrier(0);                  // rule #18 fence
      const unsigned e = srow[wl * 32 + ((i31 + 4 * (wl & 7)) & 31)];
      const unsigned nm = wavemaxu(e);                    // poked slots = 0
      if (lane == wl) k1 = nm;
    }
  }
  if (lane < KK) op[lane] = mycol;  // coalesced 20-lane store
}

// ---------------- fused dist+knn, L0 (C=3, fp32) ----------------
__global__ __launch_bounds__(1024) void fused_dist_knn0(const float* __restrict__ X4,
    const float* __restrict__ norms, int* __restrict__ idxout) {
  __shared__ unsigned sdist[16][2048];
  const int t = threadIdx.x, lane = t & 63, w = t >> 6;  // w: 0..15
  const int l15 = lane & 15, g4 = lane >> 4;
  const int bid = blockIdx.x;          // 1024
  const int b = bid & 7, g = bid >> 3; // XCD-batch affinity
  const int i0 = g * 16;

  float4 rx[4]; float ni[4];
#pragma unroll
  for (int e = 0; e < 4; ++e) {
    const int p = b * NP + i0 + g4 * 4 + e;
    rx[e] = *reinterpret_cast<const float4*>(X4 + (size_t)p * 4);
    ni[e] = norms[p];
  }

  // hoisted j-side bases: jl = it*256 + (w*16+l15); strides are constant
  const int jl0 = w * 16 + l15;
  const float* px = X4 + (size_t)(b * NP + jl0) * 4;
  const float* pn = norms + b * NP + jl0;
  const int ps0 = PHYS(jl0);
#pragma unroll
  for (int it = 0; it < 8; ++it) {
    const float4 cj = *reinterpret_cast<const float4*>(px + (size_t)it * 1024);
    const float nj = pn[it * 256];
    const int ps = ps0 + it * 256;
#pragma unroll
    for (int e = 0; e < 4; ++e) {
      float acc = fmaf(rx[e].x, cj.x, 0.f);
      acc = fmaf(rx[e].y, cj.y, acc);
      acc = fmaf(rx[e].z, cj.z, acc);
      sdist[g4 * 4 + e][ps] = packkey(2.f * acc - ni[e] - nj, jl0);
    }
  }
  __syncthreads();

  select20(&sdist[w][0], lane, idxout + (size_t)(b * NP + i0 + w) * KK);
}

// ---------------- fused dist+knn (l>=1): MFMA 16x16x32, hoisted addressing ------
template<int C>
__global__ __launch_bounds__(1024) void fused_dist_knn(const unsigned short* __restrict__ xh,
    const unsigned short* __restrict__ xl, int colbase,
    const float* __restrict__ norms, int* __restrict__ idxout) {
  constexpr int KB = C / 32;  // K-blocks per chain
  __shared__ unsigned sdist[16][2048];
  const int t = threadIdx.x, lane = t & 63, w = t >> 6;  // w: 0..15
  const int l15 = lane & 15, g4 = lane >> 4;
  const int bid = blockIdx.x;          // 1024
  const int b = bid & 7, g = bid >> 3; // XCD-batch affinity
  const int i0 = g * 16;
  const int ti = (b * NP + i0) >> 6;
  const int ir = i0 & 63;
  const int k8b = colbase >> 3;

  bf16x8 AH[KB], AL[KB];
#pragma unroll
  for (int kb = 0; kb < KB; ++kb) {
    const size_t a = (((size_t)ti * 64 + k8b + kb * 4 + g4) * 64 + ir + l15) * 8;
    AH[kb] = *reinterpret_cast<const bf16x8*>(xh + a);
    AL[kb] = *reinterpret_cast<const bf16x8*>(xl + a);
  }
  float ni[4];
#pragma unroll
  for (int e = 0; e < 4; ++e) ni[e] = norms[b * NP + i0 + g4 * 4 + e];

  // hoisted j-side bases: jr=(w*16)&63 is it-invariant; tj += 4/iter
  // -> pointer stride 4*64*64*8 = 131072 elements per iteration.
  const int tj0 = (b * NP + w * 16) >> 6;
  const int jr0 = (w * 16) & 63;
  const unsigned short* pbh[KB];
  const unsigned short* pbl[KB];
#pragma unroll
  for (int kb = 0; kb < KB; ++kb) {
    const size_t a = (((size_t)tj0 * 64 + k8b + kb * 4 + g4) * 64 + jr0 + l15) * 8;
    pbh[kb] = xh + a;
    pbl[kb] = xl + a;
  }
  const int jl0 = w * 16 + l15;
  const float* pnj = norms + b * NP + jl0;
  const int ps0 = PHYS(jl0);

#pragma unroll
  for (int it = 0; it < 8; ++it) {
    bf16x8 BH[KB], BL[KB];
#pragma unroll
    for (int kb = 0; kb < KB; ++kb) {
      BH[kb] = *reinterpret_cast<const bf16x8*>(pbh[kb] + (size_t)it * 131072);
      BL[kb] = *reinterpret_cast<const bf16x8*>(pbl[kb] + (size_t)it * 131072);
    }
    f32x4 acc = {0.f, 0.f, 0.f, 0.f};
#pragma unroll
    for (int kb = 0; kb < KB; ++kb) {
      acc = MF16(AH[kb], BH[kb], acc);
      acc = MF16(AH[kb], BL[kb], acc);
      acc = MF16(AL[kb], BH[kb], acc);
    }
    const float nj = pnj[it * 256];
    const int ps = ps0 + it * 256;
#pragma unroll
    for (int e = 0; e < 4; ++e)
      sdist[g4 * 4 + e][ps] = packkey(2.f * acc[e] - ni[e] - nj, jl0);
  }
  __syncthreads();

  select20(&sdist[w][0], lane, idxout + (size_t)(b * NP + i0 + w) * KK);
}

// ---------------- per-point GEMM, L0 (C=3, fp32 vector) ----------------
__global__ __launch_bounds__(256) void pt_gemm0(const float* __restrict__ x,
    const float* __restrict__ W, const float* __restrict__ bias,
    float* __restrict__ Y, float* __restrict__ T) {
  const int t = threadIdx.x;
  const int o = t & 63;
  const int g = blockIdx.x * 4 + (t >> 6);  // 0..16383
  const float x0 = x[(size_t)g * 3 + 0], x1 = x[(size_t)g * 3 + 1], x2 = x[(size_t)g * 3 + 2];
  const float w10 = W[o * 6 + 0], w11 = W[o * 6 + 1], w12 = W[o * 6 + 2];
  const float w20 = W[o * 6 + 3], w21 = W[o * 6 + 4], w22 = W[o * 6 + 5];
  Y[(size_t)g * 64 + o] = w10 * x0 + w11 * x1 + w12 * x2;
  T[(size_t)g * 64 + o] = (w20 - w10) * x0 + (w21 - w11) * x1 + (w22 - w12) * x2 + bias[o];
}

// ---------------- per-point GEMM (l>=1): 2 n-tiles/block, B-frag reuse ----------
template<int C, int O2>  // O2 = 2*O
__global__ __launch_bounds__(256) void pt_gemm(const unsigned short* __restrict__ xh,
    const unsigned short* __restrict__ xl, int colbase,
    const unsigned short* __restrict__ wch, const unsigned short* __restrict__ wcl,
    const float* __restrict__ bias, float* __restrict__ Y, float* __restrict__ T) {
  constexpr int K8 = C / 8;
  constexpr int H = K8 / 2;
  constexpr int O = O2 / 2;
  const int t = threadIdx.x, lane = t & 63, w = t >> 6;
  const int half = lane >> 5, l31 = lane & 31;
  const int rt = (w >> 1) * 32, tc = (w & 1) * 32;
  const int n0 = blockIdx.x * 128, o0 = blockIdx.y * 64;  // 2 n-tiles per block
  const int tn0 = n0 >> 6, tn1 = tn0 + 1, to = o0 >> 6;
  const int k8b = colbase >> 3;
  const int col = o0 + tc + l31;

  bf16x8 BH[H], BL[H];
#pragma unroll
  for (int ch = 0; ch < H; ++ch) {
    const size_t a = (((size_t)to * K8 + ch * 2 + half) * 64 + tc + l31) * 8;
    BH[ch] = *reinterpret_cast<const bf16x8*>(wch + a);
    BL[ch] = *reinterpret_cast<const bf16x8*>(wcl + a);
  }

  f32x16 acc0, acc1;
#pragma unroll
  for (int i = 0; i < 16; ++i) { acc0[i] = 0.f; acc1[i] = 0.f; }
#pragma unroll
  for (int ch = 0; ch < H; ++ch) {
    const size_t a0 = (((size_t)tn0 * 64 + k8b + ch * 2 + half) * 64 + rt + l31) * 8;
    const size_t a1 = (((size_t)tn1 * 64 + k8b + ch * 2 + half) * 64 + rt + l31) * 8;
    const bf16x8 ah0 = *reinterpret_cast<const bf16x8*>(xh + a0);
    const bf16x8 al0 = *reinterpret_cast<const bf16x8*>(xl + a0);
    const bf16x8 ah1 = *reinterpret_cast<const bf16x8*>(xh + a1);
    const bf16x8 al1 = *reinterpret_cast<const bf16x8*>(xl + a1);
    acc0 = MF(ah0, BH[ch], acc0); acc1 = MF(ah1, BH[ch], acc1);
    acc0 = MF(ah0, BL[ch], acc0); acc1 = MF(ah1, BL[ch], acc1);
    acc0 = MF(al0, BH[ch], acc0); acc1 = MF(al1, BH[ch], acc1);
  }

  if (col < O) {
#pragma unroll
    for (int i = 0; i < 16; ++i) {
      const int rr = rt + (i & 3) + 8 * (i >> 2) + 4 * half;
      Y[(size_t)(n0 + rr) * O + col] = acc0[i];
      Y[(size_t)(n0 + 64 + rr) * O + col] = acc1[i];
    }
  } else {
    const float bv = bias[col - O];
#pragma unroll
    for (int i = 0; i < 16; ++i) {
      const int rr = rt + (i & 3) + 8 * (i >> 2) + 4 * half;
      T[(size_t)(n0 + rr) * O + (col - O)] = acc0[i] + bv;
      T[(size_t)(n0 + 64 + rr) * O + (col - O)] = acc1[i] + bv;
    }
  }
}

// ---------------- edge reduce: max/sum/sumsq over gathered Y rows ----------------
template<int O, int PTS>
__global__ __launch_bounds__(256) void edge_reduce(const float* __restrict__ Y,
    const float* __restrict__ T, const int* __restrict__ idx,
    float* __restrict__ outmax, float* __restrict__ ssum, float* __restrict__ ssq) {
  constexpr int CQ = O / 4;      // channel-quad groups
  constexpr int NG = 256 / CQ;   // point groups per block
  constexpr int PPT = PTS / NG;  // points per thread
  constexpr int BPB = NP / PTS;  // blocks per batch (128)
  __shared__ int sidx[PTS * KK];
  __shared__ float sred[1024], qred[1024];
  const int t = threadIdx.x;
  const int cq = t % CQ, ng = t / CQ;
  const int c = cq * 4;
  const int bid = blockIdx.x;    // 1024 blocks total
  const int g0 = ((bid & 7) * BPB + (bid >> 3)) * PTS;  // XCD-affinity swizzle

  for (int i = t; i < PTS * KK; i += 256) sidx[i] = idx[(size_t)g0 * KK + i];
  __syncthreads();

  float s4[4] = {}, q4[4] = {};
#pragma unroll
  for (int pp = 0; pp < PPT; ++pp) {
    const int p = ng + pp * NG;
    const int g = g0 + p;
    const int base = (g >> 11) * NP;
    const float4 tv = *reinterpret_cast<const float4*>(T + (size_t)g * O + c);
    float4 vs[KK];
#pragma unroll
    for (int k = 0; k < KK; ++k)
      vs[k] = *reinterpret_cast<const float4*>(Y + (size_t)(base + sidx[p * KK + k]) * O + c);
    float m0 = -__builtin_inff(), m1 = m0, m2 = m0, m3 = m0;
#pragma unroll
    for (int k = 0; k < KK; ++k) {
      const float h0 = vs[k].x + tv.x, h1 = vs[k].y + tv.y;
      const float h2 = vs[k].z + tv.z, h3 = vs[k].w + tv.w;
      m0 = fmaxf(m0, h0); m1 = fmaxf(m1, h1); m2 = fmaxf(m2, h2); m3 = fmaxf(m3, h3);
      s4[0] += h0; s4[1] += h1; s4[2] += h2; s4[3] += h3;
      q4[0] = fmaf(h0, h0, q4[0]); q4[1] = fmaf(h1, h1, q4[1]);
      q4[2] = fmaf(h2, h2, q4[2]); q4[3] = fmaf(h3, h3, q4[3]);
    }
    float4 o4; o4.x = m0; o4.y = m1; o4.z = m2; o4.w = m3;
    *reinterpret_cast<float4*>(outmax + (size_t)g * O + c) = o4;
  }

#pragma unroll
  for (int j = 0; j < 4; ++j) { sred[t * 4 + j] = s4[j]; qred[t * 4 + j] = q4[j]; }
  __syncthreads();
  if (t < O) {
    const int cqr = t >> 2, jr = t & 3;
    float s = 0.f, q = 0.f;
#pragma unroll
    for (int n = 0; n < NG; ++n) {
      s += sred[(n * CQ + cqr) * 4 + jr];
      q += qred[(n * CQ + cqr) * 4 + jr];
    }
    atomicAdd(ssum + t, s);
    atomicAdd(ssq + t, q);
  }
}

// ---------------- bn + leaky relu -> fragment-order bf16 planes ----------------
template<int O, bool WN>
__global__ __launch_bounds__(256) void bnrelu_kernel(const float* __restrict__ fA,
    const float* __restrict__ ssum, const float* __restrict__ ssq,
    const float* __restrict__ g, const float* __restrict__ be,
    unsigned short* __restrict__ xh, unsigned short* __restrict__ xl, int colbase,
    float* __restrict__ nrm) {
  constexpr float INV = 1.0f / 327680.0f;  // B*N*K
  constexpr int K8 = O / 8;
  const int id = blockIdx.x * 256 + threadIdx.x;  // 16384*K8 items
  const int r = id & 63;
  const int k8loc = (id >> 6) % K8;
  const int tile = (id >> 6) / K8;
  const int n = tile * 64 + r;
  const int c0 = k8loc * 8;

  float hv[8];
  {
    const float4 p0 = *reinterpret_cast<const float4*>(fA + (size_t)n * O + c0);
    const float4 p1 = *reinterpret_cast<const float4*>(fA + (size_t)n * O + c0 + 4);
    hv[0] = p0.x; hv[1] = p0.y; hv[2] = p0.z; hv[3] = p0.w;
    hv[4] = p1.x; hv[5] = p1.y; hv[6] = p1.z; hv[7] = p1.w;
  }
  unsigned short hh[8], ll[8];
  float s = 0.f;
#pragma unroll
  for (int j = 0; j < 8; ++j) {
    const int col = c0 + j;
    const float m = ssum[col] * INV;
    const float v = ssq[col] * INV - m * m;
    const float sc = g[col] / sqrtf(v + 1e-5f);
    float val = (hv[j] - m) * sc + be[col];
    val = (val >= 0.f) ? val : 0.2f * val;
    split2(val, hh[j], ll[j]);
    const float recon = bff(hh[j]) + bff(ll[j]);
    s = fmaf(recon, recon, s);
  }
  const size_t ob = (((size_t)tile * 64 + (colbase >> 3) + k8loc) * 64 + r) * 8;
  uint4 ph, pl;
  ph.x = (unsigned)hh[0] | ((unsigned)hh[1] << 16);
  ph.y = (unsigned)hh[2] | ((unsigned)hh[3] << 16);
  ph.z = (unsigned)hh[4] | ((unsigned)hh[5] << 16);
  ph.w = (unsigned)hh[6] | ((unsigned)hh[7] << 16);
  pl.x = (unsigned)ll[0] | ((unsigned)ll[1] << 16);
  pl.y = (unsigned)ll[2] | ((unsigned)ll[3] << 16);
  pl.z = (unsigned)ll[4] | ((unsigned)ll[5] << 16);
  pl.w = (unsigned)ll[6] | ((unsigned)ll[7] << 16);
  *reinterpret_cast<uint4*>(xh + ob) = ph;
  *reinterpret_cast<uint4*>(xl + ob) = pl;
  if (WN) atomicAdd(nrm + n, s);
}

// ---------------- final conv + max pool: 2 n-tiles/block, B-frag reuse ----------
__global__ __launch_bounds__(256) void final_mfma(const unsigned short* __restrict__ xh,
    const unsigned short* __restrict__ wfh, unsigned* __restrict__ outenc) {
  __shared__ float fr[128];
  const int t = threadIdx.x, lane = t & 63, w = t >> 6;
  const int half = lane >> 5, l31 = lane & 31;
  const int rt = (w >> 1) * 32, tc = (w & 1) * 32;
  const int b = blockIdx.z, n0 = blockIdx.x * 128, o0 = blockIdx.y * 64;
  const int tn0 = (b * NP + n0) >> 6, tn1 = tn0 + 1, to = o0 >> 6;

  f32x16 acc0, acc1;
#pragma unroll
  for (int i = 0; i < 16; ++i) { acc0[i] = 0.f; acc1[i] = 0.f; }

#pragma unroll
  for (int cc = 0; cc < 4; ++cc) {  // 128 channels per chunk
    bf16x8 BH[8];
#pragma unroll
    for (int ch = 0; ch < 8; ++ch) {
      const int k8 = cc * 16 + ch * 2 + half;
      const size_t a = (((size_t)to * 64 + k8) * 64 + tc + l31) * 8;
      BH[ch] = *reinterpret_cast<const bf16x8*>(wfh + a);
    }
#pragma unroll
    for (int ch = 0; ch < 8; ++ch) {
      const int k8 = cc * 16 + ch * 2 + half;
      const size_t a0 = (((size_t)tn0 * 64 + k8) * 64 + rt + l31) * 8;
      const size_t a1 = (((size_t)tn1 * 64 + k8) * 64 + rt + l31) * 8;
      const bf16x8 ah0 = *reinterpret_cast<const bf16x8*>(xh + a0);
      const bf16x8 ah1 = *reinterpret_cast<const bf16x8*>(xh + a1);
      acc0 = MF(ah0, BH[ch], acc0);
      acc1 = MF(ah1, BH[ch], acc1);
    }
  }

  float M = fmaxf(acc0[0], acc1[0]);
#pragma unroll
  for (int i = 1; i < 16; ++i) M = fmaxf(M, fmaxf(acc0[i], acc1[i]));
  M = fmaxf(M, __shfl_xor(M, 32));
  fr[w * 32 + l31] = M;
  __syncthreads();
  if (t < 64) {
    const float Mc = fmaxf(fr[t], fr[64 + t]);
    const unsigned ub = __float_as_uint(Mc);
    const unsigned key = (ub & 0x80000000u) ? ~ub : (ub | 0x80000000u);
    atomicMax(outenc + b * 1024 + o0 + t, key);
  }
}

__global__ __launch_bounds__(256) void decode_kernel(const unsigned int* __restrict__ enc,
    const float* __restrict__ bf, float* __restrict__ out) {
  const int gid = blockIdx.x * 256 + threadIdx.x;  // 8192
  const unsigned key = enc[gid];
  const unsigned ubits = (key & 0x80000000u) ? (key & 0x7fffffffu) : ~key;
  out[gid] = __uint_as_float(ubits) + bf[gid & 1023];
}

// ---------------- launch ----------------
extern "C" void kernel_launch(void* const* d_in, const int* in_sizes, int n_in,
                              void* d_out, int out_size, void* d_ws, size_t ws_size,
                              hipStream_t stream) {
  (void)in_sizes; (void)n_in; (void)out_size; (void)ws_size;
  const float* x   = (const float*)d_in[0];
  const float* W0  = (const float*)d_in[1];
  const float* b0  = (const float*)d_in[2];
  const float* g0  = (const float*)d_in[3];
  const float* be0 = (const float*)d_in[4];
  const float* W1  = (const float*)d_in[5];
  const float* b1  = (const float*)d_in[6];
  const float* g1  = (const float*)d_in[7];
  const float* be1 = (const float*)d_in[8];
  const float* W2  = (const float*)d_in[9];
  const float* b2  = (const float*)d_in[10];
  const float* g2  = (const float*)d_in[11];
  const float* be2 = (const float*)d_in[12];
  const float* W3  = (const float*)d_in[13];
  const float* b3  = (const float*)d_in[14];
  const float* g3  = (const float*)d_in[15];
  const float* be3 = (const float*)d_in[16];
  const float* Wf  = (const float*)d_in[17];
  const float* bf  = (const float*)d_in[18];

  float* wsf = (float*)d_ws;
  int* idxb = (int*)d_ws;                        // 327,680 ints
  float* stats = wsf + 327680;                   // 2048
  float* nb = wsf + 329728;                      // 4 x 16384 norm buffers
  unsigned* outenc = (unsigned*)(wsf + 395264);  // 8192
  float* x4 = wsf + 403456;                      // 65536
  float* featA = wsf + 468992;                   // 16384*256
  float* negd = wsf + 4663296;                   // scratch region (Y/T)
  float* Yb = negd;
  float* Tb = negd + 4194304;
  unsigned short* xh = (unsigned short*)(wsf + 21440512);  // xT hi plane
  unsigned short* xl = xh + 8388608;                       // xT lo plane
  unsigned short* wb1 = xl + 8388608;            // 2*(2*64*64)   = 16384
  unsigned short* wb2 = wb1 + 16384;             // 2*(2*128*64)  = 32768
  unsigned short* wb3 = wb2 + 32768;             // 2*(2*256*128) = 131072
  unsigned short* wfh = wb3 + 131072;            // 1024*512
  unsigned short* wfl = wfh + 524288;

  float* normsA = nb, *normsB = nb + 16384, *normsC = nb + 32768, *normsD = nb + 49152;

  hipMemsetAsync(stats, 0, (2048 + 65536) * sizeof(float), stream);
  hipMemsetAsync(outenc, 0, 8192 * sizeof(unsigned), stream);

  const dim3 blk(256, 1, 1);
  const dim3 fblk(1024, 1, 1);
  const dim3 fgrid(1024, 1, 1);
  const dim3 ergrid(1024, 1, 1);

  pad_norms<<<dim3(64), blk, 0, stream>>>(x, x4, normsA);
  wsplit_all<<<dim3(2224), blk, 0, stream>>>(W1, W2, W3, Wf, wb1, wb2, wb3, wfh, wfl);

  // Layer 0 (C=3 -> 64, out cols [0,64))
  fused_dist_knn0<<<fgrid, fblk, 0, stream>>>(x4, normsA, idxb);
  pt_gemm0<<<dim3(4096), blk, 0, stream>>>(x, W0, b0, Yb, Tb);
  edge_reduce<64, 16><<<ergrid, blk, 0, stream>>>(Yb, Tb, idxb, featA, stats, stats + 256);
  bnrelu_kernel<64, true><<<dim3(512), blk, 0, stream>>>(featA, stats, stats + 256,
      g0, be0, xh, xl, 0, normsB);

  // Layer 1 (64 -> 64, in cols [0,64), out [64,128))
  fused_dist_knn<64><<<fgrid, fblk, 0, stream>>>(xh, xl, 0, normsB, idxb);
  pt_gemm<64, 128><<<dim3(128, 2), blk, 0, stream>>>(xh, xl, 0, wb1, wb1 + 8192, b1, Yb, Tb);
  edge_reduce<64, 16><<<ergrid, blk, 0, stream>>>(Yb, Tb, idxb, featA, stats + 512, stats + 768);
  bnrelu_kernel<64, true><<<dim3(512), blk, 0, stream>>>(featA, stats + 512, stats + 768,
      g1, be1, xh, xl, 64, normsC);

  // Layer 2 (64 -> 128, in cols [64,128), out [128,256))
  fused_dist_knn<64><<<fgrid, fblk, 0, stream>>>(xh, xl, 64, normsC, idxb);
  pt_gemm<64, 256><<<dim3(128, 4), blk, 0, stream>>>(xh, xl, 64, wb2, wb2 + 16384, b2, Yb, Tb);
  edge_reduce<128, 16><<<ergrid, blk, 0, stream>>>(Yb, Tb, idxb, featA, stats + 1024, stats + 1280);
  bnrelu_kernel<128, true><<<dim3(1024), blk, 0, stream>>>(featA, stats + 1024, stats + 1280,
      g2, be2, xh, xl, 128, normsD);

  // Layer 3 (128 -> 256, in cols [128,256), out [256,512))
  fused_dist_knn<128><<<fgrid, fblk, 0, stream>>>(xh, xl, 128, normsD, idxb);
  pt_gemm<128, 512><<<dim3(128, 8), blk, 0, stream>>>(xh, xl, 128, wb3, wb3 + 65536, b3, Yb, Tb);
  edge_reduce<256, 16><<<ergrid, blk, 0, stream>>>(Yb, Tb, idxb, featA, stats + 1536, stats + 1792);
  bnrelu_kernel<256, false><<<dim3(2048), blk, 0, stream>>>(featA, stats + 1536, stats + 1792,
      g3, be3, xh, xl, 256, nullptr);

  // Final 1x1 conv + global max pool (single-plane, 2 n-tiles/block)
  final_mfma<<<dim3(16, 16, 8), blk, 0, stream>>>(xh, wfh, outenc);
  decode_kernel<<<dim3(32), blk, 0, stream>>>(outenc, bf, (float*)d_out);
}